// Round 1
// baseline (4181.329 us; speedup 1.0000x reference)
//
#include <hip/hip_runtime.h>
#include <math.h>

// Problem constants (fixed by setup_inputs)
#define BATCH 4
#define SEQ   2048
#define CDIM  2048
#define NH    16
#define NG    4
#define HD    128

// =====================================================================
// GEMM: O[M,N] = X[M,K] @ W[N,K]^T   (all row-major, fp32, vector ALU)
// 128x128 tile, BK=16, 256 threads, 8x8 micro-tile per thread.
// A/B staged transposed in LDS (As[k][m]) so the k-loop reads are
// contiguous float4s. +4 padding keeps 16B alignment and breaks the
// worst bank strides.
// =====================================================================
template<int BK>
__global__ __launch_bounds__(256) void gemm_nt_f32(
    const float* __restrict__ X, const float* __restrict__ W,
    float* __restrict__ O, int M, int N, int K)
{
  __shared__ __align__(16) float As[BK][128 + 4];
  __shared__ __align__(16) float Bs[BK][128 + 4];
  const int tid = threadIdx.x;
  const int bm = blockIdx.x * 128;
  const int bn = blockIdx.y * 128;
  const int tx = tid & 15, ty = tid >> 4;

  float acc[8][8];
#pragma unroll
  for (int i = 0; i < 8; ++i)
#pragma unroll
    for (int j = 0; j < 8; ++j) acc[i][j] = 0.f;

  constexpr int F4_PER_ROW = BK / 4;
  constexpr int LOAD_ITERS = (128 * BK / 4) / 256;

  for (int k0 = 0; k0 < K; k0 += BK) {
#pragma unroll
    for (int it = 0; it < LOAD_ITERS; ++it) {
      int f4 = tid + it * 256;
      int r  = f4 / F4_PER_ROW;
      int kq = (f4 % F4_PER_ROW) * 4;
      float4 a = *(const float4*)(X + (size_t)(bm + r) * K + k0 + kq);
      As[kq + 0][r] = a.x; As[kq + 1][r] = a.y;
      As[kq + 2][r] = a.z; As[kq + 3][r] = a.w;
      float4 b = *(const float4*)(W + (size_t)(bn + r) * K + k0 + kq);
      Bs[kq + 0][r] = b.x; Bs[kq + 1][r] = b.y;
      Bs[kq + 2][r] = b.z; Bs[kq + 3][r] = b.w;
    }
    __syncthreads();
#pragma unroll
    for (int kk = 0; kk < BK; ++kk) {
      float a[8], b[8];
      *(float4*)&a[0] = *(const float4*)&As[kk][ty * 8];
      *(float4*)&a[4] = *(const float4*)&As[kk][ty * 8 + 4];
      *(float4*)&b[0] = *(const float4*)&Bs[kk][tx * 8];
      *(float4*)&b[4] = *(const float4*)&Bs[kk][tx * 8 + 4];
#pragma unroll
      for (int i = 0; i < 8; ++i)
#pragma unroll
        for (int j = 0; j < 8; ++j)
          acc[i][j] = fmaf(a[i], b[j], acc[i][j]);
    }
    __syncthreads();
  }
#pragma unroll
  for (int i = 0; i < 8; ++i) {
    float* orow = O + (size_t)(bm + ty * 8 + i) * N + bn + tx * 8;
    *(float4*)(orow + 0) = make_float4(acc[i][0], acc[i][1], acc[i][2], acc[i][3]);
    *(float4*)(orow + 4) = make_float4(acc[i][4], acc[i][5], acc[i][6], acc[i][7]);
  }
}

// =====================================================================
// RoPE applied in-place on q_flat [B*T, NH*HD] and k_flat [B*T, NG*HD].
// One thread per (row, head, pair). out_lo = lo*c - hi*s ; out_hi = hi*c + lo*s
// =====================================================================
__global__ __launch_bounds__(256) void rope_kernel(
    float* __restrict__ qf, float* __restrict__ kf, const int* __restrict__ off)
{
  const int idx  = blockIdx.x * 256 + threadIdx.x;
  const int qtot = BATCH * SEQ * NH * (HD / 2);
  const int ktot = BATCH * SEQ * NG * (HD / 2);
  if (idx >= qtot + ktot) return;

  float* buf; int row, head, i, cols;
  if (idx < qtot) {
    buf  = qf; cols = NH * HD;
    row  = idx / (NH * (HD / 2));
    int rem = idx % (NH * (HD / 2));
    head = rem / (HD / 2); i = rem % (HD / 2);
  } else {
    int id2 = idx - qtot;
    buf  = kf; cols = NG * HD;
    row  = id2 / (NG * (HD / 2));
    int rem = id2 % (NG * (HD / 2));
    head = rem / (HD / 2); i = rem % (HD / 2);
  }
  const int   t   = row % SEQ;
  const float pos = (float)(t + off[0]);
  const float inv = powf(10000.0f, -(float)i * (1.0f / 64.0f));
  const float ang = pos * inv;
  const float c = cosf(ang), s = sinf(ang);

  float* p = buf + (size_t)row * cols + head * HD + i;
  const float lo = p[0], hi = p[64];
  p[0]  = lo * c - hi * s;
  p[64] = hi * c + lo * s;
}

// =====================================================================
// Flash attention, fp32, causal, GQA (g = h/4).
// One block = 64 q-rows of one (b,h). KV blocks of 32; K and V share one
// LDS buffer (sequenced by barriers) to stay under the 64 KiB static LDS
// limit. Online softmax state per row in LDS (wave 0 owns it).
// LDS: Qs 33792 + KVs 16896 + Ss 8448 + state 768 = 59904 B.
// =====================================================================
#define BQ  64
#define BKV 32

__global__ __launch_bounds__(256) void attn_f32(
    const float* __restrict__ qf,  // [B,T,NH,HD]
    const float* __restrict__ kf,  // [B,T,NG,HD]
    const float* __restrict__ vf,  // [B,T,NG,HD]
    float* __restrict__ yb)        // [B,T,NH,HD]
{
  __shared__ __align__(16) float Qs[BQ][HD + 4];
  __shared__ __align__(16) float KVs[BKV][HD + 4];
  __shared__ float Ss[BQ][BKV + 1];
  __shared__ float mrow[BQ], lrow[BQ], scal[BQ];

  const int tid = threadIdx.x;
  const int bh  = blockIdx.x;           // b*NH + h
  const int b   = bh >> 4, h = bh & 15;
  const int g   = h >> 2;               // kv head
  const int qb  = blockIdx.y * BQ;

  // ---- load Q tile (row-major, padded)
  const float* qbase = qf + ((size_t)(b * SEQ + qb) * NH + h) * HD;
#pragma unroll
  for (int it = 0; it < (BQ * HD / 4) / 256; ++it) {   // 8
    int f4 = tid + it * 256;
    int r = f4 >> 5, c4 = (f4 & 31) << 2;
    *(float4*)&Qs[r][c4] = *(const float4*)(qbase + (size_t)r * (NH * HD) + c4);
  }
  if (tid < BQ) { mrow[tid] = -1e30f; lrow[tid] = 0.f; }

  float acc[8][4];
#pragma unroll
  for (int i = 0; i < 8; ++i) { acc[i][0] = 0.f; acc[i][1] = 0.f; acc[i][2] = 0.f; acc[i][3] = 0.f; }

  const int p1x = tid & 7,  p1y = tid >> 3;   // phase1: cols p1x*4.., rows p1y*2..
  const int p3x = tid & 31, p3y = tid >> 5;   // phase3: d = p3x*4.., rows p3y*8..

  const int   nkv   = qb / BKV + 2;           // block-causal: only blocks with s0 <= qb+63
  const float scale = 0.088388347648318447f;  // 1/sqrt(128)

  __syncthreads();

  for (int kb = 0; kb < nkv; ++kb) {
    const int s0 = kb * BKV;

    // ---- load K tile into KVs
    const float* kbase = kf + ((size_t)(b * SEQ + s0) * NG + g) * HD;
#pragma unroll
    for (int it = 0; it < (BKV * HD / 4) / 256; ++it) {  // 4
      int f4 = tid + it * 256;
      int r = f4 >> 5, c4 = (f4 & 31) << 2;
      *(float4*)&KVs[r][c4] = *(const float4*)(kbase + (size_t)r * (NG * HD) + c4);
    }
    __syncthreads();

    // ---- phase 1: S = Q K^T (2x4 scores per thread)
    {
      float sacc[2][4];
#pragma unroll
      for (int i = 0; i < 2; ++i)
#pragma unroll
        for (int j = 0; j < 4; ++j) sacc[i][j] = 0.f;

#pragma unroll 8
      for (int kk = 0; kk < HD; kk += 4) {
        float qv[2][4], kv[4][4];
        *(float4*)&qv[0][0] = *(const float4*)&Qs[p1y * 2 + 0][kk];
        *(float4*)&qv[1][0] = *(const float4*)&Qs[p1y * 2 + 1][kk];
#pragma unroll
        for (int j = 0; j < 4; ++j)
          *(float4*)&kv[j][0] = *(const float4*)&KVs[p1x * 4 + j][kk];
#pragma unroll
        for (int i = 0; i < 2; ++i)
#pragma unroll
          for (int j = 0; j < 4; ++j)
#pragma unroll
            for (int u = 0; u < 4; ++u)
              sacc[i][j] = fmaf(qv[i][u], kv[j][u], sacc[i][j]);
      }
#pragma unroll
      for (int i = 0; i < 2; ++i) {
        const int t = qb + p1y * 2 + i;
#pragma unroll
        for (int j = 0; j < 4; ++j) {
          const int s = s0 + p1x * 4 + j;
          Ss[p1y * 2 + i][p1x * 4 + j] = (s <= t) ? sacc[i][j] * scale : -1e30f;
        }
      }
    }
    __syncthreads();

    // ---- load V tile into KVs (K no longer needed)
    const float* vbase = vf + ((size_t)(b * SEQ + s0) * NG + g) * HD;
#pragma unroll
    for (int it = 0; it < (BKV * HD / 4) / 256; ++it) {
      int f4 = tid + it * 256;
      int r = f4 >> 5, c4 = (f4 & 31) << 2;
      *(float4*)&KVs[r][c4] = *(const float4*)(vbase + (size_t)r * (NG * HD) + c4);
    }

    // ---- phase 2: online softmax row update (wave 0 only)
    if (tid < BQ) {
      const int r = tid;
      const float m_old = mrow[r];
      float mt = m_old;
#pragma unroll 8
      for (int j = 0; j < BKV; ++j) mt = fmaxf(mt, Ss[r][j]);
      const float es = expf(m_old - mt);   // first iter: exp(-1e30) -> 0
      float sum = 0.f;
#pragma unroll 8
      for (int j = 0; j < BKV; ++j) {
        const float p = expf(Ss[r][j] - mt);
        Ss[r][j] = p;
        sum += p;
      }
      mrow[r] = mt;
      lrow[r] = lrow[r] * es + sum;
      scal[r] = es;
    }
    __syncthreads();

    // ---- rescale accumulators, then phase 3: O += P V
    {
      float sc[8];
#pragma unroll
      for (int ii = 0; ii < 8; ++ii) sc[ii] = scal[p3y * 8 + ii];
#pragma unroll
      for (int ii = 0; ii < 8; ++ii)
#pragma unroll
        for (int u = 0; u < 4; ++u) acc[ii][u] *= sc[ii];

      for (int j = 0; j < BKV; ++j) {
        float vv[4];
        *(float4*)&vv[0] = *(const float4*)&KVs[j][p3x * 4];
#pragma unroll
        for (int ii = 0; ii < 8; ++ii) {
          const float p = Ss[p3y * 8 + ii][j];
#pragma unroll
          for (int u = 0; u < 4; ++u)
            acc[ii][u] = fmaf(p, vv[u], acc[ii][u]);
        }
      }
    }
    __syncthreads();   // protect KVs before next iteration's K load
  }

  // ---- epilogue: O /= l, store y[B,T,NH,HD]
#pragma unroll
  for (int ii = 0; ii < 8; ++ii) {
    const int r = p3y * 8 + ii;
    const float inv_l = 1.0f / lrow[r];
    float4 o;
    o.x = acc[ii][0] * inv_l; o.y = acc[ii][1] * inv_l;
    o.z = acc[ii][2] * inv_l; o.w = acc[ii][3] * inv_l;
    *(float4*)(yb + ((size_t)(b * SEQ + qb + r) * NH + h) * HD + p3x * 4) = o;
  }
}

// =====================================================================
// kernel_launch
// ws layout (floats): q_flat [8192,2048] | k_flat [8192,512] |
//                     v_flat [8192,512]  | y      [8192,2048]
// total 41,943,040 floats = 160 MiB of d_ws.
// =====================================================================
extern "C" void kernel_launch(void* const* d_in, const int* in_sizes, int n_in,
                              void* d_out, int out_size, void* d_ws, size_t ws_size,
                              hipStream_t stream) {
  const float* x  = (const float*)d_in[0];
  const float* Wq = (const float*)d_in[1];
  const float* Wk = (const float*)d_in[2];
  const float* Wv = (const float*)d_in[3];
  const float* Wo = (const float*)d_in[4];
  const int*   off = (const int*)d_in[5];
  float* out = (float*)d_out;

  const int M = BATCH * SEQ;                       // 8192
  float* qf = (float*)d_ws;                        // [M, NH*HD]
  float* kf = qf + (size_t)M * CDIM;               // [M, NG*HD]
  float* vf = kf + (size_t)M * (NG * HD);          // [M, NG*HD]
  float* yb = vf + (size_t)M * (NG * HD);          // [M, NH*HD]

  dim3 blk(256);

  // projections: q = x Wq^T, k = x Wk^T, v = x Wv^T
  gemm_nt_f32<16><<<dim3(M / 128, CDIM / 128), blk, 0, stream>>>(x, Wq, qf, M, CDIM, CDIM);
  gemm_nt_f32<16><<<dim3(M / 128, (NG * HD) / 128), blk, 0, stream>>>(x, Wk, kf, M, NG * HD, CDIM);
  gemm_nt_f32<16><<<dim3(M / 128, (NG * HD) / 128), blk, 0, stream>>>(x, Wv, vf, M, NG * HD, CDIM);

  // RoPE in-place on q_flat and k_flat
  const int total_pairs = M * (NH + NG) * (HD / 2);
  rope_kernel<<<(total_pairs + 255) / 256, blk, 0, stream>>>(qf, kf, off);

  // causal GQA flash attention -> y [B,T,NH,HD] == [M, CDIM]
  attn_f32<<<dim3(BATCH * NH, SEQ / BQ), blk, 0, stream>>>(qf, kf, vf, yb);

  // output projection: out = y Wo^T
  gemm_nt_f32<16><<<dim3(M / 128, CDIM / 128), blk, 0, stream>>>(yb, Wo, out, M, CDIM, CDIM);
}

// Round 3
// 960.669 us; speedup vs baseline: 4.3525x; 4.3525x over previous
//
#include <hip/hip_runtime.h>
#include <math.h>

#define BATCH 4
#define SEQ   2048
#define CDIM  2048
#define NH    16
#define NG    4
#define HD    128
#define MTOT  (BATCH*SEQ)   // 8192
#define KVD   (NG*HD)       // 512

typedef __attribute__((ext_vector_type(8))) short     bf16x8;
typedef __attribute__((ext_vector_type(8))) unsigned short u16x8;
typedef __attribute__((ext_vector_type(4))) float     f32x4;
typedef unsigned short ushort_t;

static __device__ __forceinline__ unsigned short f2bf(float f) {
  unsigned u = __float_as_uint(f);
  u += 0x7FFF + ((u >> 16) & 1);          // round-to-nearest-even
  return (unsigned short)(u >> 16);
}
static __device__ __forceinline__ float bf2f(unsigned short h) {
  return __uint_as_float(((unsigned)h) << 16);
}

// async 16B global->LDS (linear dest = wave base + lane*16)
#define GLOAD_LDS16(gp, lp)                                                        \
  __builtin_amdgcn_global_load_lds((const __attribute__((address_space(1))) void*)(gp), \
                                   (__attribute__((address_space(3))) void*)(lp),  \
                                   16, 0, 0)

// =====================================================================
// f32 -> bf16 convert (8 elems/thread)
// =====================================================================
__global__ __launch_bounds__(256) void cvt_f32_bf16(
    const float* __restrict__ s, ushort_t* __restrict__ d, int n8)
{
  int i = blockIdx.x * 256 + threadIdx.x;
  if (i >= n8) return;
  const float4* p = (const float4*)(s + (size_t)i * 8);
  float4 a = p[0], b = p[1];
  u16x8 o;
  o[0] = f2bf(a.x); o[1] = f2bf(a.y); o[2] = f2bf(a.z); o[3] = f2bf(a.w);
  o[4] = f2bf(b.x); o[5] = f2bf(b.y); o[6] = f2bf(b.z); o[7] = f2bf(b.w);
  *(u16x8*)(d + (size_t)i * 8) = o;
}

// =====================================================================
// bf16 GEMM (m97 structure): C[M,N] = A[M,K] @ B[N,K]^T
// 128x128 tile, BK=32, 256 thr / 4 waves (2x2 of 64x64), 16x16x32 MFMA,
// global_load_lds width=16, linear LDS [128][32], 2-barrier K-loop.
// =====================================================================
template<int OUTF32>
__global__ __launch_bounds__(256) void gemm_bt_bf16(
    const ushort_t* __restrict__ A, const ushort_t* __restrict__ B,
    void* __restrict__ C, int M, int N, int K)
{
  __shared__ ushort_t As[128 * 32];
  __shared__ ushort_t Bs[128 * 32];
  const int tid  = threadIdx.x;
  const int lane = tid & 63, w = tid >> 6;
  const int wm = (w >> 1) * 64, wn = (w & 1) * 64;
  const int bm = blockIdx.x * 128, bn = blockIdx.y * 128;

  f32x4 acc[4][4];
#pragma unroll
  for (int m = 0; m < 4; ++m)
#pragma unroll
    for (int n = 0; n < 4; ++n) acc[m][n] = (f32x4){0.f, 0.f, 0.f, 0.f};

  // staging: thread tid covers LDS elems [tid*8 .. tid*8+7] (+2048 second half)
  const int srow = tid >> 2;            // 0..63
  const int scol = (tid & 3) * 8;
  const ushort_t* Ap = A + (size_t)(bm + srow) * K + scol;
  const ushort_t* Bp = B + (size_t)(bn + srow) * K + scol;

  const int fr = lane & 15, fg = lane >> 4;

  for (int k0 = 0; k0 < K; k0 += 32) {
    GLOAD_LDS16(Ap + k0,            As + tid * 8);
    GLOAD_LDS16(Ap + (size_t)64 * K + k0, As + 2048 + tid * 8);
    GLOAD_LDS16(Bp + k0,            Bs + tid * 8);
    GLOAD_LDS16(Bp + (size_t)64 * K + k0, Bs + 2048 + tid * 8);
    __syncthreads();

    bf16x8 av[4], bv[4];
#pragma unroll
    for (int m = 0; m < 4; ++m)
      av[m] = *(const bf16x8*)(As + (wm + m * 16 + fr) * 32 + fg * 8);
#pragma unroll
    for (int n = 0; n < 4; ++n)
      bv[n] = *(const bf16x8*)(Bs + (wn + n * 16 + fr) * 32 + fg * 8);
#pragma unroll
    for (int m = 0; m < 4; ++m)
#pragma unroll
      for (int n = 0; n < 4; ++n)
        acc[m][n] = __builtin_amdgcn_mfma_f32_16x16x32_bf16(av[m], bv[n], acc[m][n], 0, 0, 0);
    __syncthreads();
  }

  // C/D layout: col = lane&15, row = (lane>>4)*4 + reg  (m89-verified)
#pragma unroll
  for (int m = 0; m < 4; ++m)
#pragma unroll
    for (int n = 0; n < 4; ++n)
#pragma unroll
      for (int r = 0; r < 4; ++r) {
        const int row = bm + wm + m * 16 + fg * 4 + r;
        const int col = bn + wn + n * 16 + fr;
        if (OUTF32) ((float*)C)[(size_t)row * N + col] = acc[m][n][r];
        else        ((ushort_t*)C)[(size_t)row * N + col] = f2bf(acc[m][n][r]);
      }
}

// =====================================================================
// RoPE in-place on bf16 q [M, NH*HD] and k [M, NG*HD]
// =====================================================================
__global__ __launch_bounds__(256) void rope_bf16(
    ushort_t* __restrict__ qf, ushort_t* __restrict__ kf, const int* __restrict__ off)
{
  const int idx  = blockIdx.x * 256 + threadIdx.x;
  const int qtot = MTOT * NH * (HD / 2);
  const int ktot = MTOT * NG * (HD / 2);
  if (idx >= qtot + ktot) return;

  ushort_t* buf; int row, head, i, cols;
  if (idx < qtot) {
    buf = qf; cols = NH * HD;
    row = idx / (NH * (HD / 2));
    int rem = idx % (NH * (HD / 2));
    head = rem / (HD / 2); i = rem % (HD / 2);
  } else {
    int id2 = idx - qtot;
    buf = kf; cols = NG * HD;
    row = id2 / (NG * (HD / 2));
    int rem = id2 % (NG * (HD / 2));
    head = rem / (HD / 2); i = rem % (HD / 2);
  }
  const int   t   = row % SEQ;
  const float pos = (float)(t + off[0]);
  const float inv = powf(10000.0f, -(float)i * (1.0f / 64.0f));
  const float ang = pos * inv;
  const float c = cosf(ang), s = sinf(ang);

  ushort_t* p = buf + (size_t)row * cols + head * HD + i;
  const float lo = bf2f(p[0]), hi = bf2f(p[64]);
  p[0]  = f2bf(lo * c - hi * s);
  p[64] = f2bf(hi * c + lo * s);
}

// =====================================================================
// MFMA flash attention, causal GQA. Block = 256 thr (4 waves), BQ=64
// (16 q-rows/wave), BKV=64. Q frags live in registers (loaded once).
// K staged [64][136] (pad -> 2-way banks), V staged transposed [128][72],
// P through LDS [64][72]. Softmax fully in-register (shfl over 16 lanes).
// LDS = 17408 + 18432 + 9216 = 45056 B -> 3 blocks/CU.
// =====================================================================
#define KPAD 136
#define VPAD 72

__global__ __launch_bounds__(256) void attn_mfma(
    const ushort_t* __restrict__ qf,  // [M, NH*HD]
    const ushort_t* __restrict__ kf,  // [M, NG*HD]
    const ushort_t* __restrict__ vf,  // [M, NG*HD]
    ushort_t* __restrict__ yb)        // [M, NH*HD]
{
  __shared__ ushort_t Ks[64 * KPAD];
  __shared__ ushort_t Vt[128 * VPAD];
  __shared__ ushort_t Ps[64 * VPAD];

  const int tid  = threadIdx.x;
  const int lane = tid & 63, wq = tid >> 6;
  const int bh = blockIdx.x, b = bh >> 4, h = bh & 15, g = h >> 2;
  const int qb = blockIdx.y * 64;
  const int fr = lane & 15, fg = lane >> 4;

  // Q fragments in registers: wave's 16 rows, d = fg*8 + ds*32
  bf16x8 qv[4];
  {
    const ushort_t* qp = qf + (size_t)(b * SEQ + qb + wq * 16 + fr) * CDIM + h * HD + fg * 8;
#pragma unroll
    for (int ds = 0; ds < 4; ++ds) qv[ds] = *(const bf16x8*)(qp + ds * 32);
  }

  f32x4 o[8];
#pragma unroll
  for (int n = 0; n < 8; ++n) o[n] = (f32x4){0.f, 0.f, 0.f, 0.f};
  float mrow[4] = {-1e30f, -1e30f, -1e30f, -1e30f};
  float lrow[4] = {0.f, 0.f, 0.f, 0.f};

  const float scale = 0.088388347648318447f;   // 1/sqrt(128)
  const int nkv = qb / 64 + 1;

  for (int kb = 0; kb < nkv; ++kb) {
    const int s0 = kb * 64;
    __syncthreads();                       // previous tile's reads done

    // ---- stage K [64][128] -> Ks[64][KPAD]
#pragma unroll
    for (int it = 0; it < 4; ++it) {
      const int f4 = tid + it * 256;
      const int r = f4 >> 4, c8 = (f4 & 15) * 8;
      bf16x8 kx = *(const bf16x8*)(kf + (size_t)(b * SEQ + s0 + r) * KVD + g * HD + c8);
      *(bf16x8*)(Ks + r * KPAD + c8) = kx;
    }
    // ---- stage V transposed: Vt[d][s]
#pragma unroll
    for (int it = 0; it < 4; ++it) {
      const int f4 = tid + it * 256;
      const int r = f4 >> 4, c8 = (f4 & 15) * 8;
      bf16x8 vx = *(const bf16x8*)(vf + (size_t)(b * SEQ + s0 + r) * KVD + g * HD + c8);
#pragma unroll
      for (int j = 0; j < 8; ++j) Vt[(c8 + j) * VPAD + r] = (ushort_t)vx[j];
    }
    __syncthreads();

    // ---- S = Q K^T  (4 col-fragments x 4 d-steps)
    f32x4 st[4];
#pragma unroll
    for (int n = 0; n < 4; ++n) st[n] = (f32x4){0.f, 0.f, 0.f, 0.f};
#pragma unroll
    for (int ds = 0; ds < 4; ++ds) {
#pragma unroll
      for (int n = 0; n < 4; ++n) {
        bf16x8 kv = *(const bf16x8*)(Ks + (n * 16 + fr) * KPAD + ds * 32 + fg * 8);
        st[n] = __builtin_amdgcn_mfma_f32_16x16x32_bf16(qv[ds], kv, st[n], 0, 0, 0);
      }
    }

    // ---- online softmax (rows = wq*16 + fg*4 + r, cols = s0 + n*16 + fr)
    float es[4];
#pragma unroll
    for (int r = 0; r < 4; ++r) {
      const int grow = qb + wq * 16 + fg * 4 + r;
      float sv[4], mx = -1e30f;
#pragma unroll
      for (int n = 0; n < 4; ++n) {
        const int col = s0 + n * 16 + fr;
        float v = st[n][r] * scale;
        v = (col <= grow) ? v : -1e30f;
        sv[n] = v; mx = fmaxf(mx, v);
      }
      mx = fmaxf(mx, __shfl_xor(mx, 1, 64));
      mx = fmaxf(mx, __shfl_xor(mx, 2, 64));
      mx = fmaxf(mx, __shfl_xor(mx, 4, 64));
      mx = fmaxf(mx, __shfl_xor(mx, 8, 64));
      const float mnew = fmaxf(mrow[r], mx);
      es[r] = __expf(mrow[r] - mnew);
      float sum = 0.f;
      const int prow = (wq * 16 + fg * 4 + r) * VPAD;
#pragma unroll
      for (int n = 0; n < 4; ++n) {
        const float p = __expf(sv[n] - mnew);
        sum += p;
        Ps[prow + n * 16 + fr] = f2bf(p);
      }
      sum += __shfl_xor(sum, 1, 64);
      sum += __shfl_xor(sum, 2, 64);
      sum += __shfl_xor(sum, 4, 64);
      sum += __shfl_xor(sum, 8, 64);
      lrow[r] = lrow[r] * es[r] + sum;
      mrow[r] = mnew;
    }
    // rescale O
#pragma unroll
    for (int n = 0; n < 8; ++n)
#pragma unroll
      for (int r = 0; r < 4; ++r) o[n][r] *= es[r];

    // ---- O += P V   (A = Ps rows of this wave; B^T = Vt)
#pragma unroll
    for (int ks = 0; ks < 2; ++ks) {
      bf16x8 pa = *(const bf16x8*)(Ps + (wq * 16 + fr) * VPAD + ks * 32 + fg * 8);
#pragma unroll
      for (int n = 0; n < 8; ++n) {
        bf16x8 vb = *(const bf16x8*)(Vt + (n * 16 + fr) * VPAD + ks * 32 + fg * 8);
        o[n] = __builtin_amdgcn_mfma_f32_16x16x32_bf16(pa, vb, o[n], 0, 0, 0);
      }
    }
  }

  // ---- epilogue
#pragma unroll
  for (int n = 0; n < 8; ++n)
#pragma unroll
    for (int r = 0; r < 4; ++r) {
      const int row = qb + wq * 16 + fg * 4 + r;
      const int col = h * HD + n * 16 + fr;
      yb[(size_t)(b * SEQ + row) * CDIM + col] = f2bf(o[n][r] / lrow[r]);
    }
}

// =====================================================================
// kernel_launch
// =====================================================================
extern "C" void kernel_launch(void* const* d_in, const int* in_sizes, int n_in,
                              void* d_out, int out_size, void* d_ws, size_t ws_size,
                              hipStream_t stream) {
  const float* x  = (const float*)d_in[0];
  const float* Wq = (const float*)d_in[1];
  const float* Wk = (const float*)d_in[2];
  const float* Wv = (const float*)d_in[3];
  const float* Wo = (const float*)d_in[4];
  const int*   off = (const int*)d_in[5];
  float* out = (float*)d_out;

  ushort_t* xb  = (ushort_t*)d_ws;                    // [M, C]
  ushort_t* wqb = xb  + (size_t)MTOT * CDIM;          // [C, C]
  ushort_t* wkb = wqb + (size_t)CDIM * CDIM;          // [KVD, C]
  ushort_t* wvb = wkb + (size_t)KVD * CDIM;
  ushort_t* wob = wvb + (size_t)KVD * CDIM;           // [C, C]
  ushort_t* qb_ = wob + (size_t)CDIM * CDIM;          // [M, C]
  ushort_t* kb_ = qb_ + (size_t)MTOT * CDIM;          // [M, KVD]
  ushort_t* vb_ = kb_ + (size_t)MTOT * KVD;
  ushort_t* yb_ = vb_ + (size_t)MTOT * KVD;           // [M, C]

  dim3 blk(256);

  // convert inputs to bf16
  int n8;
  n8 = MTOT * CDIM / 8; cvt_f32_bf16<<<(n8 + 255) / 256, blk, 0, stream>>>(x,  xb,  n8);
  n8 = CDIM * CDIM / 8; cvt_f32_bf16<<<(n8 + 255) / 256, blk, 0, stream>>>(Wq, wqb, n8);
  n8 = KVD  * CDIM / 8; cvt_f32_bf16<<<(n8 + 255) / 256, blk, 0, stream>>>(Wk, wkb, n8);
  n8 = KVD  * CDIM / 8; cvt_f32_bf16<<<(n8 + 255) / 256, blk, 0, stream>>>(Wv, wvb, n8);
  n8 = CDIM * CDIM / 8; cvt_f32_bf16<<<(n8 + 255) / 256, blk, 0, stream>>>(Wo, wob, n8);

  // projections
  gemm_bt_bf16<0><<<dim3(MTOT / 128, CDIM / 128), blk, 0, stream>>>(xb, wqb, qb_, MTOT, CDIM, CDIM);
  gemm_bt_bf16<0><<<dim3(MTOT / 128, KVD / 128),  blk, 0, stream>>>(xb, wkb, kb_, MTOT, KVD, CDIM);
  gemm_bt_bf16<0><<<dim3(MTOT / 128, KVD / 128),  blk, 0, stream>>>(xb, wvb, vb_, MTOT, KVD, CDIM);

  // RoPE
  const int total_pairs = MTOT * (NH + NG) * (HD / 2);
  rope_bf16<<<(total_pairs + 255) / 256, blk, 0, stream>>>(qb_, kb_, off);

  // flash attention
  attn_mfma<<<dim3(BATCH * NH, SEQ / 64), blk, 0, stream>>>(qb_, kb_, vb_, yb_);

  // output projection (fp32 out)
  gemm_bt_bf16<1><<<dim3(MTOT / 128, CDIM / 128), blk, 0, stream>>>(yb_, wob, out, MTOT, CDIM, CDIM);
}

// Round 4
// 856.530 us; speedup vs baseline: 4.8817x; 1.1216x over previous
//
#include <hip/hip_runtime.h>
#include <math.h>

#define BATCH 4
#define SEQ   2048
#define CDIM  2048
#define NH    16
#define NG    4
#define HD    128
#define MTOT  (BATCH*SEQ)   // 8192
#define KVD   (NG*HD)       // 512

typedef __attribute__((ext_vector_type(8))) short     bf16x8;
typedef __attribute__((ext_vector_type(8))) unsigned short u16x8;
typedef __attribute__((ext_vector_type(4))) float     f32x4;
typedef unsigned short ushort_t;

static __device__ __forceinline__ unsigned short f2bf(float f) {
  unsigned u = __float_as_uint(f);
  u += 0x7FFF + ((u >> 16) & 1);          // round-to-nearest-even
  return (unsigned short)(u >> 16);
}
static __device__ __forceinline__ float bf2f(unsigned short h) {
  return __uint_as_float(((unsigned)h) << 16);
}

// async 16B global->LDS (linear dest = wave base + lane*16)
#define GLOAD_LDS16(gp, lp)                                                        \
  __builtin_amdgcn_global_load_lds((const __attribute__((address_space(1))) void*)(gp), \
                                   (__attribute__((address_space(3))) void*)(lp),  \
                                   16, 0, 0)

// =====================================================================
// f32 -> bf16 convert (8 elems/thread)
// =====================================================================
__global__ __launch_bounds__(256) void cvt_f32_bf16(
    const float* __restrict__ s, ushort_t* __restrict__ d, int n8)
{
  int i = blockIdx.x * 256 + threadIdx.x;
  if (i >= n8) return;
  const float4* p = (const float4*)(s + (size_t)i * 8);
  float4 a = p[0], b = p[1];
  u16x8 o;
  o[0] = f2bf(a.x); o[1] = f2bf(a.y); o[2] = f2bf(a.z); o[3] = f2bf(a.w);
  o[4] = f2bf(b.x); o[5] = f2bf(b.y); o[6] = f2bf(b.z); o[7] = f2bf(b.w);
  *(u16x8*)(d + (size_t)i * 8) = o;
}

// =====================================================================
// bf16 GEMM (m97 structure): C = A[M,K] @ B[N,K]^T
// OUTMODE: 0 = bf16 row-major C[M,N]; 1 = f32 row-major C[M,N];
//          2 = bf16 TRANSPOSED  C^T[N,M]  (for V^T production; LDS-tile
//              transpose in the epilogue keeps global writes coalesced)
// =====================================================================
template<int OUTMODE>
__global__ __launch_bounds__(256) void gemm_bt_bf16(
    const ushort_t* __restrict__ A, const ushort_t* __restrict__ B,
    void* __restrict__ C, int M, int N, int K)
{
  __shared__ ushort_t As[128 * 32];
  __shared__ ushort_t Bs[128 * 32];
  const int tid  = threadIdx.x;
  const int lane = tid & 63, w = tid >> 6;
  const int wm = (w >> 1) * 64, wn = (w & 1) * 64;
  const int bm = blockIdx.x * 128, bn = blockIdx.y * 128;

  f32x4 acc[4][4];
#pragma unroll
  for (int m = 0; m < 4; ++m)
#pragma unroll
    for (int n = 0; n < 4; ++n) acc[m][n] = (f32x4){0.f, 0.f, 0.f, 0.f};

  const int srow = tid >> 2;            // 0..63
  const int scol = (tid & 3) * 8;
  const ushort_t* Ap = A + (size_t)(bm + srow) * K + scol;
  const ushort_t* Bp = B + (size_t)(bn + srow) * K + scol;

  const int fr = lane & 15, fg = lane >> 4;

  for (int k0 = 0; k0 < K; k0 += 32) {
    GLOAD_LDS16(Ap + k0,                  As + tid * 8);
    GLOAD_LDS16(Ap + (size_t)64 * K + k0, As + 2048 + tid * 8);
    GLOAD_LDS16(Bp + k0,                  Bs + tid * 8);
    GLOAD_LDS16(Bp + (size_t)64 * K + k0, Bs + 2048 + tid * 8);
    __syncthreads();

    bf16x8 av[4], bv[4];
#pragma unroll
    for (int m = 0; m < 4; ++m)
      av[m] = *(const bf16x8*)(As + (wm + m * 16 + fr) * 32 + fg * 8);
#pragma unroll
    for (int n = 0; n < 4; ++n)
      bv[n] = *(const bf16x8*)(Bs + (wn + n * 16 + fr) * 32 + fg * 8);
#pragma unroll
    for (int m = 0; m < 4; ++m)
#pragma unroll
      for (int n = 0; n < 4; ++n)
        acc[m][n] = __builtin_amdgcn_mfma_f32_16x16x32_bf16(av[m], bv[n], acc[m][n], 0, 0, 0);
    __syncthreads();
  }

  // C/D layout: col = lane&15, row = (lane>>4)*4 + reg  (m89-verified)
  if constexpr (OUTMODE == 2) {
    // transpose through LDS, then coalesced b128 global writes
    __shared__ ushort_t Ct[128 * 144];
#pragma unroll
    for (int m = 0; m < 4; ++m)
#pragma unroll
      for (int n = 0; n < 4; ++n)
#pragma unroll
        for (int r = 0; r < 4; ++r)
          Ct[(wn + n * 16 + fr) * 144 + wm + m * 16 + fg * 4 + r] = f2bf(acc[m][n][r]);
    __syncthreads();
    const int col_l = tid >> 1, part = tid & 1;
    ushort_t* dst = (ushort_t*)C + (size_t)(bn + col_l) * M + bm + part * 64;
#pragma unroll
    for (int j = 0; j < 8; ++j)
      *(bf16x8*)(dst + j * 8) = *(const bf16x8*)(Ct + col_l * 144 + part * 64 + j * 8);
  } else {
#pragma unroll
    for (int m = 0; m < 4; ++m)
#pragma unroll
      for (int n = 0; n < 4; ++n)
#pragma unroll
        for (int r = 0; r < 4; ++r) {
          const int row = bm + wm + m * 16 + fg * 4 + r;
          const int col = bn + wn + n * 16 + fr;
          if (OUTMODE == 1) ((float*)C)[(size_t)row * N + col] = acc[m][n][r];
          else              ((ushort_t*)C)[(size_t)row * N + col] = f2bf(acc[m][n][r]);
        }
  }
}

// =====================================================================
// RoPE in-place on bf16 q [M, NH*HD] and k [M, NG*HD]  (V untouched)
// =====================================================================
__global__ __launch_bounds__(256) void rope_bf16(
    ushort_t* __restrict__ qf, ushort_t* __restrict__ kf, const int* __restrict__ off)
{
  const int idx  = blockIdx.x * 256 + threadIdx.x;
  const int qtot = MTOT * NH * (HD / 2);
  const int ktot = MTOT * NG * (HD / 2);
  if (idx >= qtot + ktot) return;

  ushort_t* buf; int row, head, i, cols;
  if (idx < qtot) {
    buf = qf; cols = NH * HD;
    row = idx / (NH * (HD / 2));
    int rem = idx % (NH * (HD / 2));
    head = rem / (HD / 2); i = rem % (HD / 2);
  } else {
    int id2 = idx - qtot;
    buf = kf; cols = NG * HD;
    row = id2 / (NG * (HD / 2));
    int rem = id2 % (NG * (HD / 2));
    head = rem / (HD / 2); i = rem % (HD / 2);
  }
  const int   t   = row % SEQ;
  const float pos = (float)(t + off[0]);
  const float inv = powf(10000.0f, -(float)i * (1.0f / 64.0f));
  const float ang = pos * inv;
  const float c = cosf(ang), s = sinf(ang);

  ushort_t* p = buf + (size_t)row * cols + head * HD + i;
  const float lo = bf2f(p[0]), hi = bf2f(p[64]);
  p[0]  = f2bf(lo * c - hi * s);
  p[64] = f2bf(hi * c + lo * s);
}

// =====================================================================
// MFMA flash attention, causal GQA. Block = 256 thr (4 waves), BQ=64,
// BKV=64. Q frags in registers. K staged [64][136]; V^T staged from the
// pre-transposed vT (b128 loads+stores, balanced banks) into [128][72].
// P through LDS [64][72]. Softmax in-register (shfl over 16-lane groups).
// LDS = 17408 + 18432 + 9216 = 45056 B -> 3 blocks/CU.
// =====================================================================
#define KPAD 136
#define VPAD 72

__global__ __launch_bounds__(256) void attn_mfma(
    const ushort_t* __restrict__ qf,  // [M, NH*HD]
    const ushort_t* __restrict__ kf,  // [M, NG*HD]
    const ushort_t* __restrict__ vT,  // [KVD, M]  (V^T: row = g*128+d, col = b*2048+s)
    ushort_t* __restrict__ yb)        // [M, NH*HD]
{
  __shared__ ushort_t Ks[64 * KPAD];
  __shared__ ushort_t Vt[128 * VPAD];
  __shared__ ushort_t Ps[64 * VPAD];

  const int tid  = threadIdx.x;
  const int lane = tid & 63, wq = tid >> 6;
  const int bh = blockIdx.x, b = bh >> 4, h = bh & 15, g = h >> 2;
  const int qb = blockIdx.y * 64;
  const int fr = lane & 15, fg = lane >> 4;

  // Q fragments in registers: wave's 16 rows, d = fg*8 + ds*32
  bf16x8 qv[4];
  {
    const ushort_t* qp = qf + (size_t)(b * SEQ + qb + wq * 16 + fr) * CDIM + h * HD + fg * 8;
#pragma unroll
    for (int ds = 0; ds < 4; ++ds) qv[ds] = *(const bf16x8*)(qp + ds * 32);
  }

  f32x4 o[8];
#pragma unroll
  for (int n = 0; n < 8; ++n) o[n] = (f32x4){0.f, 0.f, 0.f, 0.f};
  float mrow[4] = {-1e30f, -1e30f, -1e30f, -1e30f};
  float lrow[4] = {0.f, 0.f, 0.f, 0.f};

  const float scale = 0.088388347648318447f;   // 1/sqrt(128)
  const int nkv = qb / 64 + 1;

  const ushort_t* vtb0 = vT + (size_t)(g * HD) * MTOT + (size_t)b * SEQ;

  for (int kb = 0; kb < nkv; ++kb) {
    const int s0 = kb * 64;
    __syncthreads();                       // previous tile's reads done

    // ---- stage K [64][128] -> Ks[64][KPAD]
#pragma unroll
    for (int it = 0; it < 4; ++it) {
      const int f4 = tid + it * 256;
      const int r = f4 >> 4, c8 = (f4 & 15) * 8;
      bf16x8 kx = *(const bf16x8*)(kf + (size_t)(b * SEQ + s0 + r) * KVD + g * HD + c8);
      *(bf16x8*)(Ks + r * KPAD + c8) = kx;
    }
    // ---- stage V^T tile [128 d][64 s] -> Vt[128][VPAD] (linear b128, no transpose)
    const ushort_t* vtb = vtb0 + s0;
#pragma unroll
    for (int it = 0; it < 4; ++it) {
      const int gi = tid + it * 256;
      const int d = gi >> 3, gg = gi & 7;
      bf16x8 vx = *(const bf16x8*)(vtb + (size_t)d * MTOT + gg * 8);
      *(bf16x8*)(Vt + d * VPAD + gg * 8) = vx;
    }
    __syncthreads();

    // ---- S = Q K^T  (4 col-fragments x 4 d-steps)
    f32x4 st[4];
#pragma unroll
    for (int n = 0; n < 4; ++n) st[n] = (f32x4){0.f, 0.f, 0.f, 0.f};
#pragma unroll
    for (int ds = 0; ds < 4; ++ds) {
#pragma unroll
      for (int n = 0; n < 4; ++n) {
        bf16x8 kv = *(const bf16x8*)(Ks + (n * 16 + fr) * KPAD + ds * 32 + fg * 8);
        st[n] = __builtin_amdgcn_mfma_f32_16x16x32_bf16(qv[ds], kv, st[n], 0, 0, 0);
      }
    }

    // ---- online softmax (rows = wq*16 + fg*4 + r, cols = s0 + n*16 + fr)
    float es[4];
#pragma unroll
    for (int r = 0; r < 4; ++r) {
      const int grow = qb + wq * 16 + fg * 4 + r;
      float sv[4], mx = -1e30f;
#pragma unroll
      for (int n = 0; n < 4; ++n) {
        const int col = s0 + n * 16 + fr;
        float v = st[n][r] * scale;
        v = (col <= grow) ? v : -1e30f;
        sv[n] = v; mx = fmaxf(mx, v);
      }
      mx = fmaxf(mx, __shfl_xor(mx, 1, 64));
      mx = fmaxf(mx, __shfl_xor(mx, 2, 64));
      mx = fmaxf(mx, __shfl_xor(mx, 4, 64));
      mx = fmaxf(mx, __shfl_xor(mx, 8, 64));
      const float mnew = fmaxf(mrow[r], mx);
      es[r] = __expf(mrow[r] - mnew);
      float sum = 0.f;
      const int prow = (wq * 16 + fg * 4 + r) * VPAD;
#pragma unroll
      for (int n = 0; n < 4; ++n) {
        const float p = __expf(sv[n] - mnew);
        sum += p;
        Ps[prow + n * 16 + fr] = f2bf(p);
      }
      sum += __shfl_xor(sum, 1, 64);
      sum += __shfl_xor(sum, 2, 64);
      sum += __shfl_xor(sum, 4, 64);
      sum += __shfl_xor(sum, 8, 64);
      lrow[r] = lrow[r] * es[r] + sum;
      mrow[r] = mnew;
    }
    // rescale O
#pragma unroll
    for (int n = 0; n < 8; ++n)
#pragma unroll
      for (int r = 0; r < 4; ++r) o[n][r] *= es[r];

    // ---- O += P V   (A = Ps rows of this wave; B = Vt rows = V^T[d][s])
#pragma unroll
    for (int ks = 0; ks < 2; ++ks) {
      bf16x8 pa = *(const bf16x8*)(Ps + (wq * 16 + fr) * VPAD + ks * 32 + fg * 8);
#pragma unroll
      for (int n = 0; n < 8; ++n) {
        bf16x8 vb = *(const bf16x8*)(Vt + (n * 16 + fr) * VPAD + ks * 32 + fg * 8);
        o[n] = __builtin_amdgcn_mfma_f32_16x16x32_bf16(pa, vb, o[n], 0, 0, 0);
      }
    }
  }

  // ---- epilogue
#pragma unroll
  for (int n = 0; n < 8; ++n)
#pragma unroll
    for (int r = 0; r < 4; ++r) {
      const int row = qb + wq * 16 + fg * 4 + r;
      const int col = h * HD + n * 16 + fr;
      yb[(size_t)(b * SEQ + row) * CDIM + col] = f2bf(o[n][r] / lrow[r]);
    }
}

// =====================================================================
// kernel_launch
// =====================================================================
extern "C" void kernel_launch(void* const* d_in, const int* in_sizes, int n_in,
                              void* d_out, int out_size, void* d_ws, size_t ws_size,
                              hipStream_t stream) {
  const float* x  = (const float*)d_in[0];
  const float* Wq = (const float*)d_in[1];
  const float* Wk = (const float*)d_in[2];
  const float* Wv = (const float*)d_in[3];
  const float* Wo = (const float*)d_in[4];
  const int*   off = (const int*)d_in[5];
  float* out = (float*)d_out;

  ushort_t* xb  = (ushort_t*)d_ws;                    // [M, C]
  ushort_t* wqb = xb  + (size_t)MTOT * CDIM;          // [C, C]
  ushort_t* wkb = wqb + (size_t)CDIM * CDIM;          // [KVD, C]
  ushort_t* wvb = wkb + (size_t)KVD * CDIM;
  ushort_t* wob = wvb + (size_t)KVD * CDIM;           // [C, C]
  ushort_t* qb_ = wob + (size_t)CDIM * CDIM;          // [M, C]
  ushort_t* kb_ = qb_ + (size_t)MTOT * CDIM;          // [M, KVD]
  ushort_t* vT_ = kb_ + (size_t)MTOT * KVD;           // [KVD, M]  (V^T)
  ushort_t* yb_ = vT_ + (size_t)MTOT * KVD;           // [M, C]

  dim3 blk(256);

  // convert inputs to bf16
  int n8;
  n8 = MTOT * CDIM / 8; cvt_f32_bf16<<<(n8 + 255) / 256, blk, 0, stream>>>(x,  xb,  n8);
  n8 = CDIM * CDIM / 8; cvt_f32_bf16<<<(n8 + 255) / 256, blk, 0, stream>>>(Wq, wqb, n8);
  n8 = KVD  * CDIM / 8; cvt_f32_bf16<<<(n8 + 255) / 256, blk, 0, stream>>>(Wk, wkb, n8);
  n8 = KVD  * CDIM / 8; cvt_f32_bf16<<<(n8 + 255) / 256, blk, 0, stream>>>(Wv, wvb, n8);
  n8 = CDIM * CDIM / 8; cvt_f32_bf16<<<(n8 + 255) / 256, blk, 0, stream>>>(Wo, wob, n8);

  // projections (V written transposed)
  gemm_bt_bf16<0><<<dim3(MTOT / 128, CDIM / 128), blk, 0, stream>>>(xb, wqb, qb_, MTOT, CDIM, CDIM);
  gemm_bt_bf16<0><<<dim3(MTOT / 128, KVD / 128),  blk, 0, stream>>>(xb, wkb, kb_, MTOT, KVD, CDIM);
  gemm_bt_bf16<2><<<dim3(MTOT / 128, KVD / 128),  blk, 0, stream>>>(xb, wvb, vT_, MTOT, KVD, CDIM);

  // RoPE (q, k only)
  const int total_pairs = MTOT * (NH + NG) * (HD / 2);
  rope_bf16<<<(total_pairs + 255) / 256, blk, 0, stream>>>(qb_, kb_, off);

  // flash attention
  attn_mfma<<<dim3(BATCH * NH, SEQ / 64), blk, 0, stream>>>(qb_, kb_, vT_, yb_);

  // output projection (fp32 out)
  gemm_bt_bf16<1><<<dim3(MTOT / 128, CDIM / 128), blk, 0, stream>>>(yb_, wob, out, MTOT, CDIM, CDIM);
}

// Round 5
// 720.224 us; speedup vs baseline: 5.8056x; 1.1893x over previous
//
#include <hip/hip_runtime.h>
#include <math.h>

#define BATCH 4
#define SEQ   2048
#define CDIM  2048
#define NH    16
#define NG    4
#define HD    128
#define MTOT  (BATCH*SEQ)   // 8192
#define KVD   (NG*HD)       // 512

typedef __attribute__((ext_vector_type(8))) short     bf16x8;
typedef __attribute__((ext_vector_type(8))) unsigned short u16x8;
typedef __attribute__((ext_vector_type(4))) float     f32x4;
typedef unsigned short ushort_t;

static __device__ __forceinline__ unsigned short f2bf(float f) {
  unsigned u = __float_as_uint(f);
  u += 0x7FFF + ((u >> 16) & 1);          // round-to-nearest-even
  return (unsigned short)(u >> 16);
}
static __device__ __forceinline__ float bf2f(unsigned short h) {
  return __uint_as_float(((unsigned)h) << 16);
}

// async 16B global->LDS (linear dest = wave base + lane*16)
#define GLOAD_LDS16(gp, lp)                                                        \
  __builtin_amdgcn_global_load_lds((const __attribute__((address_space(1))) void*)(gp), \
                                   (__attribute__((address_space(3))) void*)(lp),  \
                                   16, 0, 0)

// =====================================================================
// f32 -> bf16 convert (8 elems/thread)
// =====================================================================
__global__ __launch_bounds__(256) void cvt_f32_bf16(
    const float* __restrict__ s, ushort_t* __restrict__ d, int n8)
{
  int i = blockIdx.x * 256 + threadIdx.x;
  if (i >= n8) return;
  const float4* p = (const float4*)(s + (size_t)i * 8);
  float4 a = p[0], b = p[1];
  u16x8 o;
  o[0] = f2bf(a.x); o[1] = f2bf(a.y); o[2] = f2bf(a.z); o[3] = f2bf(a.w);
  o[4] = f2bf(b.x); o[5] = f2bf(b.y); o[6] = f2bf(b.z); o[7] = f2bf(b.w);
  *(u16x8*)(d + (size_t)i * 8) = o;
}

// =====================================================================
// bf16 GEMM (m97 structure): C = A[M,K] @ B[N,K]^T
// OUTMODE: 0 = bf16 C[M,N]; 1 = f32 C[M,N]; 2 = bf16 C^T[N,M] (V^T)
// =====================================================================
template<int OUTMODE>
__global__ __launch_bounds__(256) void gemm_bt_bf16(
    const ushort_t* __restrict__ A, const ushort_t* __restrict__ B,
    void* __restrict__ C, int M, int N, int K)
{
  __shared__ ushort_t As[128 * 32];
  __shared__ ushort_t Bs[128 * 32];
  const int tid  = threadIdx.x;
  const int lane = tid & 63, w = tid >> 6;
  const int wm = (w >> 1) * 64, wn = (w & 1) * 64;
  const int bm = blockIdx.x * 128, bn = blockIdx.y * 128;

  f32x4 acc[4][4];
#pragma unroll
  for (int m = 0; m < 4; ++m)
#pragma unroll
    for (int n = 0; n < 4; ++n) acc[m][n] = (f32x4){0.f, 0.f, 0.f, 0.f};

  const int srow = tid >> 2;            // 0..63
  const int scol = (tid & 3) * 8;
  const ushort_t* Ap = A + (size_t)(bm + srow) * K + scol;
  const ushort_t* Bp = B + (size_t)(bn + srow) * K + scol;

  const int fr = lane & 15, fg = lane >> 4;

  for (int k0 = 0; k0 < K; k0 += 32) {
    GLOAD_LDS16(Ap + k0,                  As + tid * 8);
    GLOAD_LDS16(Ap + (size_t)64 * K + k0, As + 2048 + tid * 8);
    GLOAD_LDS16(Bp + k0,                  Bs + tid * 8);
    GLOAD_LDS16(Bp + (size_t)64 * K + k0, Bs + 2048 + tid * 8);
    __syncthreads();

    bf16x8 av[4], bv[4];
#pragma unroll
    for (int m = 0; m < 4; ++m)
      av[m] = *(const bf16x8*)(As + (wm + m * 16 + fr) * 32 + fg * 8);
#pragma unroll
    for (int n = 0; n < 4; ++n)
      bv[n] = *(const bf16x8*)(Bs + (wn + n * 16 + fr) * 32 + fg * 8);
#pragma unroll
    for (int m = 0; m < 4; ++m)
#pragma unroll
      for (int n = 0; n < 4; ++n)
        acc[m][n] = __builtin_amdgcn_mfma_f32_16x16x32_bf16(av[m], bv[n], acc[m][n], 0, 0, 0);
    __syncthreads();
  }

  // C/D layout: col = lane&15, row = (lane>>4)*4 + reg  (m89-verified)
  if constexpr (OUTMODE == 2) {
    __shared__ ushort_t Ct[128 * 144];
#pragma unroll
    for (int m = 0; m < 4; ++m)
#pragma unroll
      for (int n = 0; n < 4; ++n)
#pragma unroll
        for (int r = 0; r < 4; ++r)
          Ct[(wn + n * 16 + fr) * 144 + wm + m * 16 + fg * 4 + r] = f2bf(acc[m][n][r]);
    __syncthreads();
    const int col_l = tid >> 1, part = tid & 1;
    ushort_t* dst = (ushort_t*)C + (size_t)(bn + col_l) * M + bm + part * 64;
#pragma unroll
    for (int j = 0; j < 8; ++j)
      *(bf16x8*)(dst + j * 8) = *(const bf16x8*)(Ct + col_l * 144 + part * 64 + j * 8);
  } else {
#pragma unroll
    for (int m = 0; m < 4; ++m)
#pragma unroll
      for (int n = 0; n < 4; ++n)
#pragma unroll
        for (int r = 0; r < 4; ++r) {
          const int row = bm + wm + m * 16 + fg * 4 + r;
          const int col = bn + wn + n * 16 + fr;
          if (OUTMODE == 1) ((float*)C)[(size_t)row * N + col] = acc[m][n][r];
          else              ((ushort_t*)C)[(size_t)row * N + col] = f2bf(acc[m][n][r]);
        }
  }
}

// =====================================================================
// RoPE in-place on bf16 q [M, NH*HD] and k [M, NG*HD]  (V untouched)
// =====================================================================
__global__ __launch_bounds__(256) void rope_bf16(
    ushort_t* __restrict__ qf, ushort_t* __restrict__ kf, const int* __restrict__ off)
{
  const int idx  = blockIdx.x * 256 + threadIdx.x;
  const int qtot = MTOT * NH * (HD / 2);
  const int ktot = MTOT * NG * (HD / 2);
  if (idx >= qtot + ktot) return;

  ushort_t* buf; int row, head, i, cols;
  if (idx < qtot) {
    buf = qf; cols = NH * HD;
    row = idx / (NH * (HD / 2));
    int rem = idx % (NH * (HD / 2));
    head = rem / (HD / 2); i = rem % (HD / 2);
  } else {
    int id2 = idx - qtot;
    buf = kf; cols = NG * HD;
    row = id2 / (NG * (HD / 2));
    int rem = id2 % (NG * (HD / 2));
    head = rem / (HD / 2); i = rem % (HD / 2);
  }
  const int   t   = row % SEQ;
  const float pos = (float)(t + off[0]);
  const float inv = powf(10000.0f, -(float)i * (1.0f / 64.0f));
  const float ang = pos * inv;
  const float c = cosf(ang), s = sinf(ang);

  ushort_t* p = buf + (size_t)row * cols + head * HD + i;
  const float lo = bf2f(p[0]), hi = bf2f(p[64]);
  p[0]  = f2bf(lo * c - hi * s);
  p[64] = f2bf(hi * c + lo * s);
}

// =====================================================================
// MFMA flash attention v2, causal GQA. 256 thr / 4 waves; BQ=128
// (32 q-rows per wave -> 2x MFMA density), BKV=64. Async-stage split:
// next K/V tile prefetched into regs during compute, ds_written after
// the barrier (T14). Scale folded into exp2 argument. Wave-uniform skip
// of fully-masked tiles; column-mask only on diagonal tiles.
// LDS: Ks 64x136 (17408) + Vt 128x72 (18432) + Ps 128x72 (18432) = 54272 B.
// =====================================================================
#define KPAD 136
#define VPAD 72

__global__ __launch_bounds__(256, 2) void attn_mfma(
    const ushort_t* __restrict__ qf,  // [M, NH*HD]
    const ushort_t* __restrict__ kf,  // [M, NG*HD]
    const ushort_t* __restrict__ vT,  // [KVD, M]  (V^T: row = g*128+d, col = b*2048+s)
    ushort_t* __restrict__ yb)        // [M, NH*HD]
{
  __shared__ ushort_t Ks[64 * KPAD];
  __shared__ ushort_t Vt[128 * VPAD];
  __shared__ ushort_t Ps[128 * VPAD];

  const int tid  = threadIdx.x;
  const int lane = tid & 63, wq = tid >> 6;
  const int bh = blockIdx.x, b = bh >> 4, h = bh & 15, g = h >> 2;
  const int qb = blockIdx.y * 128;
  const int fr = lane & 15, fg = lane >> 4;
  const int wrow0 = qb + wq * 32;           // wave's first q-row

  // Q fragments in registers: 2 row-blocks x 4 d-steps
  bf16x8 qv[2][4];
#pragma unroll
  for (int rb = 0; rb < 2; ++rb) {
    const ushort_t* qp = qf + (size_t)(b * SEQ + wrow0 + rb * 16 + fr) * CDIM + h * HD + fg * 8;
#pragma unroll
    for (int ds = 0; ds < 4; ++ds) qv[rb][ds] = *(const bf16x8*)(qp + ds * 32);
  }

  f32x4 o[2][8];
#pragma unroll
  for (int rb = 0; rb < 2; ++rb)
#pragma unroll
    for (int n = 0; n < 8; ++n) o[rb][n] = (f32x4){0.f, 0.f, 0.f, 0.f};
  float mrow[2][4], lrow[2][4];
#pragma unroll
  for (int rb = 0; rb < 2; ++rb)
#pragma unroll
    for (int r = 0; r < 4; ++r) { mrow[rb][r] = -1e30f; lrow[rb][r] = 0.f; }

  const float K2 = 0.12751743671f;          // (1/sqrt(128)) * log2(e)
  const int nkv = qb / 64 + 2;

  const ushort_t* vtb0 = vT + (size_t)(g * HD) * MTOT + (size_t)b * SEQ;
  const ushort_t* kfb  = kf + (size_t)(b * SEQ) * KVD + g * HD;

  bf16x8 kpre[4], vpre[4];

  auto prefetch = [&](int s0n) {
#pragma unroll
    for (int it = 0; it < 4; ++it) {
      const int f4 = tid + it * 256;
      kpre[it] = *(const bf16x8*)(kfb + (size_t)(s0n + (f4 >> 4)) * KVD + (f4 & 15) * 8);
    }
#pragma unroll
    for (int it = 0; it < 4; ++it) {
      const int f4 = tid + it * 256;
      vpre[it] = *(const bf16x8*)(vtb0 + s0n + (size_t)(f4 >> 3) * MTOT + (f4 & 7) * 8);
    }
  };
  auto writetile = [&]() {
#pragma unroll
    for (int it = 0; it < 4; ++it) {
      const int f4 = tid + it * 256;
      *(bf16x8*)(Ks + (f4 >> 4) * KPAD + (f4 & 15) * 8) = kpre[it];
    }
#pragma unroll
    for (int it = 0; it < 4; ++it) {
      const int f4 = tid + it * 256;
      *(bf16x8*)(Vt + (f4 >> 3) * VPAD + (f4 & 7) * 8) = vpre[it];
    }
  };

  prefetch(0);
  writetile();
  __syncthreads();

  for (int kb = 0; kb < nkv; ++kb) {
    const int s0 = kb * 64;
    const bool last = (kb + 1 >= nkv);
    if (!last) prefetch(s0 + 64);          // overlap HBM latency with compute

    if (s0 <= wrow0 + 31) {                // wave-uniform: tile touches this wave's rows
      // ---- S = Q K^T
      f32x4 st[2][4];
#pragma unroll
      for (int rb = 0; rb < 2; ++rb)
#pragma unroll
        for (int n = 0; n < 4; ++n) st[rb][n] = (f32x4){0.f, 0.f, 0.f, 0.f};
      __builtin_amdgcn_s_setprio(1);
#pragma unroll
      for (int ds = 0; ds < 4; ++ds)
#pragma unroll
        for (int n = 0; n < 4; ++n) {
          bf16x8 kvf = *(const bf16x8*)(Ks + (n * 16 + fr) * KPAD + ds * 32 + fg * 8);
          st[0][n] = __builtin_amdgcn_mfma_f32_16x16x32_bf16(qv[0][ds], kvf, st[0][n], 0, 0, 0);
          st[1][n] = __builtin_amdgcn_mfma_f32_16x16x32_bf16(qv[1][ds], kvf, st[1][n], 0, 0, 0);
        }
      __builtin_amdgcn_s_setprio(0);

      // ---- online softmax (raw scores; scale folded into exp2 arg)
      const bool nomask = (s0 + 63 <= wrow0);
      float es[2][4];
#pragma unroll
      for (int rb = 0; rb < 2; ++rb)
#pragma unroll
        for (int r = 0; r < 4; ++r) {
          const int grow = wrow0 + rb * 16 + fg * 4 + r;
          float sv[4], mx = -1e30f;
#pragma unroll
          for (int n = 0; n < 4; ++n) {
            float v = st[rb][n][r];
            if (!nomask) {
              const int col = s0 + n * 16 + fr;
              v = (col <= grow) ? v : -1e30f;
            }
            sv[n] = v; mx = fmaxf(mx, v);
          }
          mx = fmaxf(mx, __shfl_xor(mx, 1, 64));
          mx = fmaxf(mx, __shfl_xor(mx, 2, 64));
          mx = fmaxf(mx, __shfl_xor(mx, 4, 64));
          mx = fmaxf(mx, __shfl_xor(mx, 8, 64));
          const float mnew = fmaxf(mrow[rb][r], mx);
          es[rb][r] = exp2f((mrow[rb][r] - mnew) * K2);
          float sum = 0.f;
          const int prow = (wq * 32 + rb * 16 + fg * 4 + r) * VPAD;
#pragma unroll
          for (int n = 0; n < 4; ++n) {
            const float p = exp2f((sv[n] - mnew) * K2);
            sum += p;
            Ps[prow + n * 16 + fr] = f2bf(p);
          }
          sum += __shfl_xor(sum, 1, 64);
          sum += __shfl_xor(sum, 2, 64);
          sum += __shfl_xor(sum, 4, 64);
          sum += __shfl_xor(sum, 8, 64);
          lrow[rb][r] = lrow[rb][r] * es[rb][r] + sum;
          mrow[rb][r] = mnew;
        }
      // rescale O
#pragma unroll
      for (int rb = 0; rb < 2; ++rb)
#pragma unroll
        for (int n = 0; n < 8; ++n)
#pragma unroll
          for (int r = 0; r < 4; ++r) o[rb][n][r] *= es[rb][r];

      // ---- O += P V  (P rows are this wave's own strip -> no barrier needed)
      __builtin_amdgcn_s_setprio(1);
#pragma unroll
      for (int ks = 0; ks < 2; ++ks) {
        bf16x8 pa0 = *(const bf16x8*)(Ps + (wq * 32 + fr) * VPAD + ks * 32 + fg * 8);
        bf16x8 pa1 = *(const bf16x8*)(Ps + (wq * 32 + 16 + fr) * VPAD + ks * 32 + fg * 8);
#pragma unroll
        for (int n = 0; n < 8; ++n) {
          bf16x8 vbf = *(const bf16x8*)(Vt + (n * 16 + fr) * VPAD + ks * 32 + fg * 8);
          o[0][n] = __builtin_amdgcn_mfma_f32_16x16x32_bf16(pa0, vbf, o[0][n], 0, 0, 0);
          o[1][n] = __builtin_amdgcn_mfma_f32_16x16x32_bf16(pa1, vbf, o[1][n], 0, 0, 0);
        }
      }
      __builtin_amdgcn_s_setprio(0);
    }

    __syncthreads();                        // all waves done reading Ks/Vt
    if (!last) writetile();                 // stage next tile (regs already in flight)
    __syncthreads();                        // staged tile visible
  }

  // ---- epilogue
#pragma unroll
  for (int rb = 0; rb < 2; ++rb)
#pragma unroll
    for (int n = 0; n < 8; ++n)
#pragma unroll
      for (int r = 0; r < 4; ++r) {
        const int row = qb + wq * 32 + rb * 16 + fg * 4 + r;
        const int col = h * HD + n * 16 + fr;
        yb[(size_t)(b * SEQ + row) * CDIM + col] = f2bf(o[rb][n][r] / lrow[rb][r]);
      }
}

// =====================================================================
// kernel_launch
// =====================================================================
extern "C" void kernel_launch(void* const* d_in, const int* in_sizes, int n_in,
                              void* d_out, int out_size, void* d_ws, size_t ws_size,
                              hipStream_t stream) {
  const float* x  = (const float*)d_in[0];
  const float* Wq = (const float*)d_in[1];
  const float* Wk = (const float*)d_in[2];
  const float* Wv = (const float*)d_in[3];
  const float* Wo = (const float*)d_in[4];
  const int*   off = (const int*)d_in[5];
  float* out = (float*)d_out;

  ushort_t* xb  = (ushort_t*)d_ws;                    // [M, C]
  ushort_t* wqb = xb  + (size_t)MTOT * CDIM;          // [C, C]
  ushort_t* wkb = wqb + (size_t)CDIM * CDIM;          // [KVD, C]
  ushort_t* wvb = wkb + (size_t)KVD * CDIM;
  ushort_t* wob = wvb + (size_t)KVD * CDIM;           // [C, C]
  ushort_t* qb_ = wob + (size_t)CDIM * CDIM;          // [M, C]
  ushort_t* kb_ = qb_ + (size_t)MTOT * CDIM;          // [M, KVD]
  ushort_t* vT_ = kb_ + (size_t)MTOT * KVD;           // [KVD, M]  (V^T)
  ushort_t* yb_ = vT_ + (size_t)MTOT * KVD;           // [M, C]

  dim3 blk(256);

  // convert inputs to bf16
  int n8;
  n8 = MTOT * CDIM / 8; cvt_f32_bf16<<<(n8 + 255) / 256, blk, 0, stream>>>(x,  xb,  n8);
  n8 = CDIM * CDIM / 8; cvt_f32_bf16<<<(n8 + 255) / 256, blk, 0, stream>>>(Wq, wqb, n8);
  n8 = KVD  * CDIM / 8; cvt_f32_bf16<<<(n8 + 255) / 256, blk, 0, stream>>>(Wk, wkb, n8);
  n8 = KVD  * CDIM / 8; cvt_f32_bf16<<<(n8 + 255) / 256, blk, 0, stream>>>(Wv, wvb, n8);
  n8 = CDIM * CDIM / 8; cvt_f32_bf16<<<(n8 + 255) / 256, blk, 0, stream>>>(Wo, wob, n8);

  // projections (V written transposed)
  gemm_bt_bf16<0><<<dim3(MTOT / 128, CDIM / 128), blk, 0, stream>>>(xb, wqb, qb_, MTOT, CDIM, CDIM);
  gemm_bt_bf16<0><<<dim3(MTOT / 128, KVD / 128),  blk, 0, stream>>>(xb, wkb, kb_, MTOT, KVD, CDIM);
  gemm_bt_bf16<2><<<dim3(MTOT / 128, KVD / 128),  blk, 0, stream>>>(xb, wvb, vT_, MTOT, KVD, CDIM);

  // RoPE (q, k only)
  const int total_pairs = MTOT * (NH + NG) * (HD / 2);
  rope_bf16<<<(total_pairs + 255) / 256, blk, 0, stream>>>(qb_, kb_, off);

  // flash attention (BQ=128)
  attn_mfma<<<dim3(BATCH * NH, SEQ / 128), blk, 0, stream>>>(qb_, kb_, vT_, yb_);

  // output projection (fp32 out)
  gemm_bt_bf16<1><<<dim3(MTOT / 128, CDIM / 128), blk, 0, stream>>>(yb_, wob, out, MTOT, CDIM, CDIM);
}